// Round 6
// baseline (88.036 us; speedup 1.0000x reference)
//
#include <hip/hip_runtime.h>

// SGCN fused: out[n,d,t,w] = sum_v (sum_c x[n,c,t,v]*W[c,d] + b[d]) * a[n,t,v,w]
// plus exact f32 copy of a into d_out second region.
// N=64, C_IN=C_OUT=64, T=300, V=25.
// Block = 512 threads (8 waves), owns (n, 12 t) = 3 chunks x 4 t, pipelined:
//   scatter(k) -> barrier -> issue loads(k+1) -> compute(k)+stores -> barrier.
// Wave wid: tl = wid>>1 (t within chunk), dh = wid&1 (32-row d-half).
// W fragments/bias/addr math hoisted out of the chunk loop.

typedef __attribute__((ext_vector_type(8))) short short8;
typedef __attribute__((ext_vector_type(4))) float f32x4;

#define XS_S 66   // Wt/Xs row stride (ushort)
#define YS_S 36   // Ys row stride
#define AT_S 36   // At row stride

__device__ __forceinline__ unsigned short f2bf(float f) {
    unsigned int u = __builtin_bit_cast(unsigned int, f);
    return (unsigned short)((u + 0x7FFFu + ((u >> 16) & 1u)) >> 16);
}

__global__ __launch_bounds__(512, 4)
void sgcn_fused(const float* __restrict__ xg, const float* __restrict__ ag,
                const float* __restrict__ Wg, const float* __restrict__ bg,
                float* __restrict__ outg)
{
    __shared__ alignas(16) unsigned short Wt[64 * XS_S];      // W^T [d][c]
    __shared__ alignas(16) unsigned short Xs[4 * 32 * XS_S];  // x [tl][v][c]
    __shared__ alignas(16) unsigned short At[4 * 32 * AT_S];  // a^T [tl][w][v]
    __shared__ alignas(16) unsigned short Ys[8 * 32 * YS_S];  // y [wave][dl][v]

    const int tid  = threadIdx.x;
    const int wid  = tid >> 6;
    const int lane = tid & 63;
    const int q    = lane >> 4;   // 0..3
    const int lo   = lane & 15;   // 0..15

    const int bid = blockIdx.x;
    const int n   = bid / 25;
    const int t0  = (bid % 25) * 12;

    // ---- W load (once per block) ----
    f32x4 wv[2];
#pragma unroll
    for (int m = 0; m < 2; ++m)
        wv[m] = *(const f32x4*)(Wg + 4 * (tid + 512 * m));

    // ---- At pad columns v=25..31 zero (once; scatter never writes them) ----
    if (tid < 128) {
        unsigned short* ar = &At[(tid >> 5) * (32 * AT_S) + (tid & 31) * AT_S];
#pragma unroll
        for (int i = 25; i < 32; ++i) ar[i] = 0;
    }

    // ---- hoisted scatter address math + chunk-0 load issue ----
    long xbase = ((long)n * 64 * 300 + t0) * 25;
    long abase = ((long)n * 300 + t0) * 625;

    int xc[4], xj[4];
    f32x4 xv[4];
#pragma unroll
    for (int m = 0; m < 4; ++m) {
        const int f = tid + 512 * m;
        xc[m] = f / 25; xj[m] = f % 25;
        if (m < 3 || f < 1600)
            xv[m] = *(const f32x4*)(xg + xbase + (long)xc[m] * 7500 + 4 * xj[m]);
    }
    f32x4 av[2];
#pragma unroll
    for (int m = 0; m < 2; ++m) {
        const int f = tid + 512 * m;
        if (m < 1 || f < 625)
            av[m] = *(const f32x4*)(ag + abase + 4 * f);
    }

    // ---- stage W -> Wt[d][c] ----
#pragma unroll
    for (int m = 0; m < 2; ++m) {
        const int f = 4 * (tid + 512 * m);
#pragma unroll
        for (int i = 0; i < 4; ++i) {
            const int e = f + i, c = e >> 6, d = e & 63;
            Wt[d * XS_S + c] = f2bf(wv[m][i]);
        }
    }
    __syncthreads();   // Wt + At pads ready

    // ---- hoisted per-wave constants ----
    const int tl = wid >> 1;
    const int dh = wid & 1;
    const int d0 = 32 * dh;

    short8 wfrag[2][2];
#pragma unroll
    for (int mi = 0; mi < 2; ++mi)
#pragma unroll
        for (int ki = 0; ki < 2; ++ki)
            wfrag[mi][ki] = *(const short8*)&Wt[(d0 + 16 * mi + lo) * XS_S + 32 * ki + 8 * q];

    f32x4 bias[2];
#pragma unroll
    for (int mi = 0; mi < 2; ++mi)
#pragma unroll
        for (int r = 0; r < 4; ++r)
            bias[mi][r] = bg[d0 + 16 * mi + 4 * q + r];

    const unsigned short* xs = Xs + tl * (32 * XS_S);
    unsigned short*       ys = Ys + wid * (32 * YS_S);
    const unsigned short* at = At + tl * (32 * AT_S);

    for (int kc = 0; kc < 3; ++kc) {
        // ---- scatter current chunk regs -> LDS (+ a f32 copy-out) ----
#pragma unroll
        for (int m = 0; m < 4; ++m) {
            const int f = tid + 512 * m;
            if (m < 3 || f < 1600) {
#pragma unroll
                for (int i = 0; i < 4; ++i) {
                    const int e = 4 * xj[m] + i;      // 0..99 within 4-t row
                    const int tc = e / 25, v = e % 25;
                    Xs[tc * (32 * XS_S) + v * XS_S + xc[m]] = f2bf(xv[m][i]);
                }
            }
        }
        {
            float* aout = outg + 30720000L + abase;
#pragma unroll
            for (int m = 0; m < 2; ++m) {
                const int f = tid + 512 * m;
                if (m < 1 || f < 625) {
                    *(f32x4*)(aout + 4 * f) = av[m];
#pragma unroll
                    for (int i = 0; i < 4; ++i) {
                        const int e = 4 * f + i;       // (t,v,w) flat
                        const int tc = e / 625, r = e % 625;
                        At[tc * (32 * AT_S) + (r % 25) * AT_S + (r / 25)] = f2bf(av[m][i]);
                    }
                }
            }
        }
        const int t = t0 + 4 * kc + tl;
        __syncthreads();   // staging visible to all waves

        // ---- issue next chunk's loads; they fly under this chunk's compute ----
        if (kc < 2) {
            xbase += 100;  abase += 2500;
#pragma unroll
            for (int m = 0; m < 4; ++m) {
                const int f = tid + 512 * m;
                if (m < 3 || f < 1600)
                    xv[m] = *(const f32x4*)(xg + xbase + (long)xc[m] * 7500 + 4 * xj[m]);
            }
#pragma unroll
            for (int m = 0; m < 2; ++m) {
                const int f = tid + 512 * m;
                if (m < 1 || f < 625)
                    av[m] = *(const f32x4*)(ag + abase + 4 * f);
            }
        }

        // ---- step 1: y[dl,v] = b + sum_c W[c,d] x[c,v]  (M=32,N=32pad,K=64) ----
        f32x4 accy[2][2];
#pragma unroll
        for (int mi = 0; mi < 2; ++mi) { accy[mi][0] = bias[mi]; accy[mi][1] = bias[mi]; }
#pragma unroll
        for (int ni = 0; ni < 2; ++ni)
#pragma unroll
            for (int ki = 0; ki < 2; ++ki) {
                const short8 bf = *(const short8*)&xs[(16 * ni + lo) * XS_S + 32 * ki + 8 * q];
#pragma unroll
                for (int mi = 0; mi < 2; ++mi)
                    accy[mi][ni] = __builtin_amdgcn_mfma_f32_16x16x32_bf16(
                        wfrag[mi][ki], bf, accy[mi][ni], 0, 0, 0);
            }

        // ---- y -> Ys (per-wave private; pad cols -> 0; no barrier needed) ----
#pragma unroll
        for (int mi = 0; mi < 2; ++mi)
#pragma unroll
            for (int ni = 0; ni < 2; ++ni) {
                const int v = 16 * ni + lo;
                const bool ok = (v < 25);
#pragma unroll
                for (int r = 0; r < 4; ++r)
                    ys[(16 * mi + 4 * q + r) * YS_S + v] =
                        ok ? f2bf(accy[mi][ni][r]) : (unsigned short)0;
            }

        // ---- step 2 (swapped): O^T[w,dl] = sum_v a^T[w,v] y[dl,v] ----
        short8 afr[2];
#pragma unroll
        for (int mi = 0; mi < 2; ++mi)
            afr[mi] = *(const short8*)&at[(16 * mi + lo) * AT_S + 8 * q];
        short8 yfr[2];
#pragma unroll
        for (int dj = 0; dj < 2; ++dj)
            yfr[dj] = *(const short8*)&ys[(16 * dj + lo) * YS_S + 8 * q];

        f32x4 acco[2][2];
#pragma unroll
        for (int mi = 0; mi < 2; ++mi)
#pragma unroll
            for (int dj = 0; dj < 2; ++dj)
                acco[mi][dj] = f32x4{0.f, 0.f, 0.f, 0.f};
#pragma unroll
        for (int mi = 0; mi < 2; ++mi)
#pragma unroll
            for (int dj = 0; dj < 2; ++dj)
                acco[mi][dj] = __builtin_amdgcn_mfma_f32_16x16x32_bf16(
                    afr[mi], yfr[dj], acco[mi][dj], 0, 0, 0);

        // ---- store out[n,d,t,w]; lane's 4 regs = consecutive w ----
        float* op = outg + ((long)n * 64 * 300 + t) * 25;
#pragma unroll
        for (int dj = 0; dj < 2; ++dj) {
            const long dbase = (long)(d0 + 16 * dj + lo) * 7500;
            *(f32x4*)(op + dbase + 4 * q) = acco[0][dj];          // w = 4q..4q+3
            if (q < 2)
                *(f32x4*)(op + dbase + 16 + 4 * q) = acco[1][dj]; // w = 16..23
            else if (q == 2)
                op[dbase + 24] = acco[1][dj][0];                  // w = 24
        }

        __syncthreads();   // all Xs/At reads done before next scatter
    }
}

extern "C" void kernel_launch(void* const* d_in, const int* in_sizes, int n_in,
                              void* d_out, int out_size, void* d_ws, size_t ws_size,
                              hipStream_t stream) {
    const float* x = (const float*)d_in[0];
    const float* a = (const float*)d_in[1];
    const float* W = (const float*)d_in[2];
    const float* b = (const float*)d_in[3];
    float* out = (float*)d_out;
    hipLaunchKernelGGL(sgcn_fused, dim3(64 * 25), dim3(512), 0, stream,
                       x, a, W, b, out);
}

// Round 7
// 87.150 us; speedup vs baseline: 1.0102x; 1.0102x over previous
//
#include <hip/hip_runtime.h>

// SGCN fused: out[n,d,t,w] = sum_v (sum_c x[n,c,t,v]*W[c,d] + b[d]) * a[n,t,v,w]
// plus exact f32 copy of a into d_out second region.
// N=64, C_IN=C_OUT=64, T=300, V=25.
//
// Grid-level specialization (one launch, 5400 blocks of 512 threads):
//   bid % 9 == 8  -> COPY block  (600): pure streaming a -> out2, 5000 float4 each.
//   else          -> COMPUTE block (4800): R3 structure, handles (n, 4 t),
//                    wave wid: tl = wid>>1 (t), dh = wid&1 (32-row d-half).
// Copy waves keep HBM queues full while compute waves stall on barriers/MFMA.

typedef __attribute__((ext_vector_type(8))) short short8;
typedef __attribute__((ext_vector_type(4))) float f32x4;

#define XS_S 66   // Wt/Xs row stride (ushort)
#define YS_S 36   // Ys row stride
#define AT_S 36   // At row stride

__device__ __forceinline__ unsigned short f2bf(float f) {
    unsigned int u = __builtin_bit_cast(unsigned int, f);
    return (unsigned short)((u + 0x7FFFu + ((u >> 16) & 1u)) >> 16);
}

__global__ __launch_bounds__(512, 6)
void sgcn_fused(const float* __restrict__ xg, const float* __restrict__ ag,
                const float* __restrict__ Wg, const float* __restrict__ bg,
                float* __restrict__ outg)
{
    __shared__ alignas(16) unsigned short Wt[64 * XS_S];      // W^T [d][c]
    __shared__ alignas(16) unsigned short Xs[4 * 32 * XS_S];  // x [tl][v][c]
    __shared__ alignas(16) unsigned short Ys[8 * 32 * YS_S];  // y [wave][dl][v]
    __shared__ alignas(16) unsigned short At[4 * 32 * AT_S];  // a^T [tl][w][v]

    const int tid = threadIdx.x;
    const int bid = blockIdx.x;

    // ======================= COPY BLOCKS ===================================
    if (bid % 9 == 8) {
        const int ci = bid / 9;                 // 0..599
        const long base = (long)ci * 5000;      // float4 units; 600*5000 = 3,000,000
        const float* src = ag;
        float* dst = outg + 30720000L;
        f32x4 v[10];
#pragma unroll
        for (int m = 0; m < 10; ++m) {
            const int ib = m * 512 + tid;
            if (ib < 5000)
                v[m] = *(const f32x4*)(src + 4 * (base + ib));
        }
#pragma unroll
        for (int m = 0; m < 10; ++m) {
            const int ib = m * 512 + tid;
            if (ib < 5000)
                *(f32x4*)(dst + 4 * (base + ib)) = v[m];
        }
        return;
    }

    // ======================= COMPUTE BLOCKS ================================
    const int cb  = bid - bid / 9;              // 0..4799
    const int n   = cb / 75;
    const int t0  = (cb % 75) * 4;

    const int wid  = tid >> 6;
    const int lane = tid & 63;
    const int q    = lane >> 4;   // 0..3
    const int lo   = lane & 15;   // 0..15

    // ---------------- issue all global loads (independent, early) ----------
    // x slab: 64 c-rows x 100 floats (4 t's) = 1600 float4
    f32x4 xv[4];
    const long xbase = ((long)n * 64 * 300 + t0) * 25;
#pragma unroll
    for (int m = 0; m < 4; ++m) {
        const int f = tid + 512 * m;
        if (m < 3 || f < 1600) {
            const int c = f / 25, j = f % 25;
            xv[m] = *(const f32x4*)(xg + xbase + (long)c * 7500 + 4 * j);
        }
    }
    // a slab: 2500 floats = 625 float4
    f32x4 av[2];
    const long abase = ((long)n * 300 + t0) * 625;
#pragma unroll
    for (int m = 0; m < 2; ++m) {
        const int f = tid + 512 * m;
        if (m < 1 || f < 625)
            av[m] = *(const f32x4*)(ag + abase + 4 * f);
    }
    // W: 4096 floats = 1024 float4
    f32x4 wv[2];
#pragma unroll
    for (int m = 0; m < 2; ++m)
        wv[m] = *(const f32x4*)(Wg + 4 * (tid + 512 * m));

    // ---------------- zero At pad columns v=25..31 (K-dim of step 2) -------
    if (tid < 128) {   // 4 tl * 32 w-rows
        unsigned short* ar = &At[(tid >> 5) * (32 * AT_S) + (tid & 31) * AT_S];
#pragma unroll
        for (int i = 25; i < 32; ++i) ar[i] = 0;
    }

    // ---------------- scatter to LDS (bf16) --------------------------------
    // W -> Wt[d][c]
#pragma unroll
    for (int m = 0; m < 2; ++m) {
        const int f = 4 * (tid + 512 * m);
#pragma unroll
        for (int i = 0; i < 4; ++i) {
            const int e = f + i, c = e >> 6, d = e & 63;
            Wt[d * XS_S + c] = f2bf(wv[m][i]);
        }
    }
    // x -> Xs[tl][v][c]
#pragma unroll
    for (int m = 0; m < 4; ++m) {
        const int f = tid + 512 * m;
        if (m < 3 || f < 1600) {
            const int c = f / 25, j = f % 25;
#pragma unroll
            for (int i = 0; i < 4; ++i) {
                const int e = 4 * j + i;          // 0..99 within the 4-t row
                const int tl = e / 25, v = e % 25;
                Xs[tl * (32 * XS_S) + v * XS_S + c] = f2bf(xv[m][i]);
            }
        }
    }
    // a -> At[tl][w][v] (bf16 only; f32 copy handled by copy blocks)
#pragma unroll
    for (int m = 0; m < 2; ++m) {
        const int f = tid + 512 * m;
        if (m < 1 || f < 625) {
#pragma unroll
            for (int i = 0; i < 4; ++i) {
                const int e = 4 * f + i;       // (t,v,w) flat
                const int tl = e / 625, r = e % 625;
                At[tl * (32 * AT_S) + (r % 25) * AT_S + (r / 25)] = f2bf(av[m][i]);
            }
        }
    }
    __syncthreads();   // staging complete

    // ---------------- per-wave compute: t = t0 + tl, d in [32*dh, 32*dh+32) -
    const int tl = wid >> 1;
    const int dh = wid & 1;
    const int t  = t0 + tl;
    const int d0 = 32 * dh;

    short8 wfrag[2][2];
#pragma unroll
    for (int mi = 0; mi < 2; ++mi)
#pragma unroll
        for (int ki = 0; ki < 2; ++ki)
            wfrag[mi][ki] = *(const short8*)&Wt[(d0 + 16 * mi + lo) * XS_S + 32 * ki + 8 * q];

    f32x4 bias[2];
#pragma unroll
    for (int mi = 0; mi < 2; ++mi)
#pragma unroll
        for (int r = 0; r < 4; ++r)
            bias[mi][r] = bg[d0 + 16 * mi + 4 * q + r];

    // step 1: y[dl,v] = b + sum_c W[c,d] x[c,v]   (M=32, N=32pad, K=64)
    const unsigned short* xs = Xs + tl * (32 * XS_S);
    f32x4 accy[2][2];
#pragma unroll
    for (int mi = 0; mi < 2; ++mi) { accy[mi][0] = bias[mi]; accy[mi][1] = bias[mi]; }
#pragma unroll
    for (int ni = 0; ni < 2; ++ni)
#pragma unroll
        for (int ki = 0; ki < 2; ++ki) {
            const short8 bf = *(const short8*)&xs[(16 * ni + lo) * XS_S + 32 * ki + 8 * q];
#pragma unroll
            for (int mi = 0; mi < 2; ++mi)
                accy[mi][ni] = __builtin_amdgcn_mfma_f32_16x16x32_bf16(
                    wfrag[mi][ki], bf, accy[mi][ni], 0, 0, 0);
        }

    // y -> Ys[dl][v] (bf16, pad cols -> 0); per-wave private, no barrier
    unsigned short* ys = Ys + wid * (32 * YS_S);
#pragma unroll
    for (int mi = 0; mi < 2; ++mi)
#pragma unroll
        for (int ni = 0; ni < 2; ++ni) {
            const int v = 16 * ni + lo;
            const bool ok = (v < 25);
#pragma unroll
            for (int r = 0; r < 4; ++r)
                ys[(16 * mi + 4 * q + r) * YS_S + v] =
                    ok ? f2bf(accy[mi][ni][r]) : (unsigned short)0;
        }

    // step 2 (swapped): O^T[w, dl] = sum_v a^T[w,v] * y[dl,v]
    const unsigned short* at = At + tl * (32 * AT_S);
    short8 afr[2];
#pragma unroll
    for (int mi = 0; mi < 2; ++mi)
        afr[mi] = *(const short8*)&at[(16 * mi + lo) * AT_S + 8 * q];
    short8 yfr[2];
#pragma unroll
    for (int dj = 0; dj < 2; ++dj)
        yfr[dj] = *(const short8*)&ys[(16 * dj + lo) * YS_S + 8 * q];

    f32x4 acco[2][2];
#pragma unroll
    for (int mi = 0; mi < 2; ++mi)
#pragma unroll
        for (int dj = 0; dj < 2; ++dj)
            acco[mi][dj] = f32x4{0.f, 0.f, 0.f, 0.f};
#pragma unroll
    for (int mi = 0; mi < 2; ++mi)
#pragma unroll
        for (int dj = 0; dj < 2; ++dj)
            acco[mi][dj] = __builtin_amdgcn_mfma_f32_16x16x32_bf16(
                afr[mi], yfr[dj], acco[mi][dj], 0, 0, 0);

    // store: D[row = w = 16mi+4q+r][col = dl = 16dj+lo] -> out[n, d, t, w]
    float* op = outg + ((long)n * 64 * 300 + t) * 25;
#pragma unroll
    for (int dj = 0; dj < 2; ++dj) {
        const long dbase = (long)(d0 + 16 * dj + lo) * 7500;
        *(f32x4*)(op + dbase + 4 * q) = acco[0][dj];          // w = 4q..4q+3
        if (q < 2)
            *(f32x4*)(op + dbase + 16 + 4 * q) = acco[1][dj]; // w = 16..23
        else if (q == 2)
            op[dbase + 24] = acco[1][dj][0];                  // w = 24
    }
}

extern "C" void kernel_launch(void* const* d_in, const int* in_sizes, int n_in,
                              void* d_out, int out_size, void* d_ws, size_t ws_size,
                              hipStream_t stream) {
    const float* x = (const float*)d_in[0];
    const float* a = (const float*)d_in[1];
    const float* W = (const float*)d_in[2];
    const float* b = (const float*)d_in[3];
    float* out = (float*)d_out;
    // 4800 compute blocks + 600 copy blocks, interleaved (bid%9==8 -> copy)
    hipLaunchKernelGGL(sgcn_fused, dim3(5400), dim3(512), 0, stream,
                       x, a, W, b, out);
}